// Round 7
// baseline (688.164 us; speedup 1.0000x reference)
//
#include <hip/hip_runtime.h>
#include <hip/hip_bf16.h>

// Problem constants: N=32, C_IN=C_OUT=64, T=512, V=25, S=3, R=32
// ws layout
#define XM_OFF   0             // 51200 f32
#define SSUM_OFF 51200         // 64
#define SSQ_OFF  51264         // 64
#define SCL_OFF  51328         // 64
#define SHF_OFF  51392         // 64
#define W3F_BYTE_OFF  (51456ull * 4ull)              // w3 frag pack: 3*4*2*64*16B = 24576 B
#define ATTF_BYTE_OFF (W3F_BYTE_OFF + 24576ull)      // attf bf16 frag: 12.58 MB
#define Y_BYTE_OFF    (ATTF_BYTE_OFF + 12582912ull)  // bf16 y: 26214400 elems = 52.4 MB

typedef __attribute__((ext_vector_type(8))) short short8;
typedef __attribute__((ext_vector_type(4))) float f32x4;

__device__ __forceinline__ ushort f2bs(float f) {
  __hip_bfloat16 h = __float2bfloat16(f);
  ushort u; __builtin_memcpy(&u, &h, 2); return u;
}
__device__ __forceinline__ float bs2f(ushort u) {
  return __uint_as_float((unsigned)u << 16);
}

// ---------------------------------------------------------------------------
// K1: xm[n,c,v] = mean_t x[n,c,t,v]; block per (n,c). Also zero BN stat accums.
__global__ __launch_bounds__(256) void k_xm(const float* __restrict__ x,
                                            float* __restrict__ ws) {
  const int b = blockIdx.x;            // n*64 + c
  const int tid = threadIdx.x;
  if (b == 0 && tid < 128) ws[SSUM_OFF + tid] = 0.f;   // zero ssum+ssq
  const float* base = x + (size_t)b * 12800;
  float acc[25];
#pragma unroll
  for (int v = 0; v < 25; ++v) acc[v] = 0.f;
  for (int t = tid; t < 512; t += 256) {
    const float* row = base + t * 25;
#pragma unroll
    for (int v = 0; v < 25; ++v) acc[v] += row[v];
  }
  __shared__ float red[256][25];
#pragma unroll
  for (int v = 0; v < 25; ++v) red[tid][v] = acc[v];
  __syncthreads();
  for (int st = 128; st > 0; st >>= 1) {
    if (tid < st) {
#pragma unroll
      for (int v = 0; v < 25; ++v) red[tid][v] += red[tid + st][v];
    }
    __syncthreads();
  }
  if (tid < 25) ws[XM_OFF + b * 25 + tid] = red[0][tid] * (1.0f / 512.0f);
}

// ---------------------------------------------------------------------------
// K2: att -> bf16 MFMA-A-fragment layout attf[(n*3+s)*64+o][mt(2)][lane(64)][8]
__global__ __launch_bounds__(256) void k_att(const float* __restrict__ ws,
    const float* __restrict__ A, const float* __restrict__ w1, const float* __restrict__ b1,
    const float* __restrict__ w2, const float* __restrict__ b2, const float* __restrict__ w4,
    const float* __restrict__ b4, const float* __restrict__ alpha, uint* __restrict__ attf) {
  const int b = blockIdx.x;
  const int n = b / 24; const int r = b % 24; const int s = r >> 3; const int og = r & 7;
  const int tid = threadIdx.x;
  __shared__ float xs[1600];   // xm[n][c][v]
  __shared__ float qb[800];    // q[r][v]
  __shared__ float kb[800];    // k[r][v]
  __shared__ float att8[8][625];
  for (int j = tid; j < 1600; j += 256) xs[j] = ws[XM_OFF + n * 1600 + j];
  __syncthreads();
  for (int i = tid; i < 1600; i += 256) {
    const int half = i / 800;
    const int ii = i % 800;
    const int rr = ii / 25, v = ii % 25;
    const float* w = half ? w2 : w1;
    const float* bb = half ? b2 : b1;
    float acc = bb[s * 32 + rr];
    const float* wr = w + (s * 32 + rr) * 64;
#pragma unroll 8
    for (int c = 0; c < 64; ++c) acc += wr[c] * xs[c * 25 + v];
    (half ? kb : qb)[ii] = acc;
  }
  __syncthreads();
  const float al = alpha[s];
  for (int i = tid; i < 5000; i += 256) {
    const int o2 = i / 625, r2 = i % 625;
    const int u = r2 / 25, v = r2 % 25;
    const int o = og * 8 + o2;
    const float* wr = w4 + (s * 64 + o) * 32;
    float acc = 0.f;
#pragma unroll 8
    for (int rr2 = 0; rr2 < 32; ++rr2) {
      const float d = qb[rr2 * 25 + u] - kb[rr2 * 25 + v];
      acc += wr[rr2] * fmaxf(d, 0.f);
    }
    att8[o2][r2] = (acc + b4[s * 64 + o]) * al + A[s * 625 + r2];
  }
  __syncthreads();
  // emit frag layout: per o, 512 u32 words: word = mt*256 + lane*4 + pr
  for (int w = tid; w < 4096; w += 256) {
    const int o2 = w >> 9, widx = w & 511;
    const int mt = widx >> 8, lane = (widx >> 2) & 63, pr = widx & 3;
    const int kg = lane >> 4, colu = lane & 15;
    const int u = mt * 16 + colu;
    const int i0 = pr * 2;
    const int v0 = kg * 4 + (i0 & 3) + ((i0 >> 2) << 4);
    const float f0 = (u < 25 && v0 < 25) ? att8[o2][u * 25 + v0] : 0.f;
    const float f1 = (u < 25 && (v0 + 1) < 25) ? att8[o2][u * 25 + v0 + 1] : 0.f;
    attf[((size_t)(n * 3 + s) * 64 + og * 8 + o2) * 512 + widx] =
        (uint)f2bs(f0) | ((uint)f2bs(f1) << 16);
  }
}

// ---------------------------------------------------------------------------
// K2b: pack w3 into A-fragment order: w3f[((s*4+mt)*2+kb)*64+lane] = short8
__global__ __launch_bounds__(512) void k_wpack(const float* __restrict__ w3,
                                               short8* __restrict__ w3f) {
  const int s = blockIdx.x;
  const int tid = threadIdx.x;
  const int mt = tid >> 7, kb2 = (tid >> 6) & 1, lane = tid & 63;
  const int kg = lane >> 4, col = lane & 15;
  const int o = mt * 16 + col;
  const float* wrow = w3 + ((size_t)s * 64 + o) * 64;
  const float4 lo = *(const float4*)(wrow + kb2 * 32 + kg * 4);
  const float4 hi = *(const float4*)(wrow + kb2 * 32 + 16 + kg * 4);
  short8 a;
  a[0] = (short)f2bs(lo.x); a[1] = (short)f2bs(lo.y);
  a[2] = (short)f2bs(lo.z); a[3] = (short)f2bs(lo.w);
  a[4] = (short)f2bs(hi.x); a[5] = (short)f2bs(hi.y);
  a[6] = (short)f2bs(hi.z); a[7] = (short)f2bs(hi.w);
  w3f[((s * 4 + mt) * 2 + kb2) * 64 + lane] = a;
}

// ---------------------------------------------------------------------------
// K3: fused conv3 + aggregation, o-split. Block=(n, t-chunk 16, o-half 32).
// 512 thr = 8 waves; LDS 81664B -> 2 blocks/CU (4 waves/SIMD).
__global__ __launch_bounds__(512, 4) void k_fused(const float* __restrict__ x,
    const short8* __restrict__ w3f, const float* __restrict__ b3,
    const ushort* __restrict__ attf, float* __restrict__ ssum, float* __restrict__ ssq,
    ushort* __restrict__ yg) {
  __shared__ ushort xl[2][25][64][8];     // 51200 B, conv3 B-frag order (R2-proven)
  __shared__ ushort vs[15232];            // [t16][v28][o34] 30464 B; later y-pack [32][408]
  const int bid = blockIdx.x;
  // XCD swizzle: 256 blocks per XCD cover 4 n x 32 tc x 2 oh (o-twin + same-n share L2)
  const int xcd = bid & 7, j = bid >> 3;
  const int n = xcd * 4 + (j >> 6);
  const int r0 = j & 63;
  const int tc = r0 >> 1, oh = r0 & 1;
  const int t0 = tc << 4;
  const int tid = threadIdx.x;
  const int lane = tid & 63, wid = tid >> 6;
  const int kg = lane >> 4, col = lane & 15;

  // zero vs (v-pad slots 25..27 must be 0; they are never overwritten)
  {
    uint* vz = (uint*)vs;
    for (int i = tid; i < 7616; i += 512) vz[i] = 0u;
  }
  // stage x slab -> frag-order bf16 (coalesced dword reads, 8B LDS writes)
  if (tid < 400) {
    const float* xb = x + (size_t)n * 819200 + t0 * 25 + tid;
    const int scol = tid & 15, snt = tid >> 4;
#pragma unroll
    for (int cq = 0; cq < 16; ++cq) {
      const int c0 = cq * 4;
      const float f0 = xb[(size_t)(c0 + 0) * 12800];
      const float f1 = xb[(size_t)(c0 + 1) * 12800];
      const float f2 = xb[(size_t)(c0 + 2) * 12800];
      const float f3 = xb[(size_t)(c0 + 3) * 12800];
      ushort4 p;
      p.x = f2bs(f0); p.y = f2bs(f1); p.z = f2bs(f2); p.w = f2bs(f3);
      *(ushort4*)&xl[c0 >> 5][snt][(cq & 3) * 16 + scol][((c0 >> 4) & 1) * 4] = p;
    }
  }

  f32x4 yacc[4][2];
#pragma unroll
  for (int oi = 0; oi < 4; ++oi) { yacc[oi][0] = (f32x4)0.f; yacc[oi][1] = (f32x4)0.f; }

  const int od_l = wid << 2;              // wave's local o base (0..28)
  const int og0 = oh << 5;                // block's global o offset

  __syncthreads();

  for (int s = 0; s < 3; ++s) {
    // ---- A-frags (pre-packed) + bias
    short8 af[2][2];
    float4 b3f[2];
#pragma unroll
    for (int mt = 0; mt < 2; ++mt) {
      const int mt_abs = (oh << 1) + mt;
#pragma unroll
      for (int kb2 = 0; kb2 < 2; ++kb2)
        af[mt][kb2] = w3f[((s * 4 + mt_abs) * 2 + kb2) * 64 + lane];
      b3f[mt] = *(const float4*)(b3 + s * 64 + og0 + mt * 16 + kg * 4);
    }

    // ---- conv3: B = 2x ds_read_b128; C -> vs via 2x b32 writes per (nt,mt)
    for (int nt = wid; nt < 25; nt += 8) {
      const short8 bf0 = *(const short8*)&xl[0][nt][lane][0];
      const short8 bf1 = *(const short8*)&xl[1][nt][lane][0];
      const int item = nt * 16 + col;
      const int t = item / 25;
      const int v = item - t * 25;
      const int vsbase = (t * 28 + v) * 34;
#pragma unroll
      for (int mt = 0; mt < 2; ++mt) {
        f32x4 acc;
        acc[0] = b3f[mt].x; acc[1] = b3f[mt].y; acc[2] = b3f[mt].z; acc[3] = b3f[mt].w;
        acc = __builtin_amdgcn_mfma_f32_16x16x32_bf16(af[mt][0], bf0, acc, 0, 0, 0);
        acc = __builtin_amdgcn_mfma_f32_16x16x32_bf16(af[mt][1], bf1, acc, 0, 0, 0);
        uint* dst = (uint*)&vs[vsbase + mt * 16 + kg * 4];
        dst[0] = (uint)f2bs(acc[0]) | ((uint)f2bs(acc[1]) << 16);
        dst[1] = (uint)f2bs(acc[2]) | ((uint)f2bs(acc[3]) << 16);
      }
    }
    __syncthreads();

    // ---- agg: A = attf b128 x2 (k>=25 slots are zero there), B from vs
    const ushort* apb = attf + (((size_t)(n * 3 + s) * 64 + og0 + od_l) << 10);
#pragma unroll
    for (int oi = 0; oi < 4; ++oi) {
      const ushort* ap = apb + ((size_t)oi << 10);
      const short8 A0 = *(const short8*)(ap + lane * 8);
      const short8 A1 = *(const short8*)(ap + 512 + lane * 8);
      const int o_l = od_l + oi;
      short8 bfr;
#pragma unroll
      for (int i = 0; i < 8; ++i) {
        int v = kg * 4 + (i & 3) + ((i >> 2) << 4);
        v = (v < 28) ? v : 27;            // v>=28 -> zero pad slot (A is 0 there anyway)
        bfr[i] = (short)vs[(col * 28 + v) * 34 + o_l];
      }
      yacc[oi][0] = __builtin_amdgcn_mfma_f32_16x16x32_bf16(A0, bfr, yacc[oi][0], 0, 0, 0);
      yacc[oi][1] = __builtin_amdgcn_mfma_f32_16x16x32_bf16(A1, bfr, yacc[oi][1], 0, 0, 0);
    }
    __syncthreads();   // vs free for next s
  }

  // ---- BN partial stats: (wave, oi) owns one o entirely (16 t x 25 u)
#pragma unroll
  for (int oi = 0; oi < 4; ++oi) {
    float a1 = 0.f, a2 = 0.f;
#pragma unroll
    for (int mt = 0; mt < 2; ++mt) {
#pragma unroll
      for (int r2 = 0; r2 < 4; ++r2) {
        const int u = mt * 16 + kg * 4 + r2;
        if (u < 25) {
          const float vv = yacc[oi][mt][r2];
          a1 += vv; a2 += vv * vv;
        }
      }
    }
#pragma unroll
    for (int off = 32; off > 0; off >>= 1) {
      a1 += __shfl_down(a1, off);
      a2 += __shfl_down(a2, off);
    }
    if (lane == 0) {
      atomicAdd(&ssum[og0 + od_l + oi], a1);
      atomicAdd(&ssq[og0 + od_l + oi], a2);
    }
  }

  // ---- pack y into vs as [o32][408], then coalesced int4 stores
#pragma unroll
  for (int oi = 0; oi < 4; ++oi) {
    const int o_l = od_l + oi;
#pragma unroll
    for (int mt = 0; mt < 2; ++mt) {
#pragma unroll
      for (int r2 = 0; r2 < 4; ++r2) {
        const int u = mt * 16 + kg * 4 + r2;
        if (u < 25) vs[o_l * 408 + col * 25 + u] = f2bs(yacc[oi][mt][r2]);
      }
    }
  }
  __syncthreads();
  {
    const size_t ybase = ((size_t)n * 64 + og0) * 12800 + (size_t)t0 * 25;
    for (int k2 = tid; k2 < 1600; k2 += 512) {
      const int o = k2 / 50, rem = k2 - o * 50;
      *(int4*)(yg + ybase + (size_t)o * 12800 + rem * 8) = *(const int4*)&vs[o * 408 + rem * 8];
    }
  }
}

// ---------------------------------------------------------------------------
// K4: BN train-mode stats -> scale/shift
__global__ __launch_bounds__(64) void k_stats(const float* __restrict__ ssum,
    const float* __restrict__ ssq, const float* __restrict__ gamma,
    const float* __restrict__ beta, float* __restrict__ scl, float* __restrict__ shf) {
  const int o = threadIdx.x;
  const float inv = 1.0f / 409600.0f;          // N*T*V
  const float mu = ssum[o] * inv;
  const float var = ssq[o] * inv - mu * mu;    // biased
  const float rstd = rsqrtf(var + 1e-5f);
  const float sc = gamma[o] * rstd;
  scl[o] = sc;
  shf[o] = beta[o] - mu * sc;
}

// ---------------------------------------------------------------------------
// K5: out = relu(y) + y*scale[o] + shift[o] + x
__global__ __launch_bounds__(256) void k_final(const float* __restrict__ x,
    const ushort* __restrict__ yg, const float* __restrict__ scl,
    const float* __restrict__ shf, float* __restrict__ out) {
  const int stride = gridDim.x * blockDim.x;
  for (int i = blockIdx.x * 256 + threadIdx.x; i < 6553600; i += stride) {
    const int o = (i / 3200) & 63;             // 3200 float4 per (n,o) slab
    const float sc = scl[o], sh = shf[o];
    const float4 xv = ((const float4*)x)[i];
    const ushort4 yu = ((const ushort4*)yg)[i];
    const float y0 = bs2f(yu.x), y1 = bs2f(yu.y), y2 = bs2f(yu.z), y3 = bs2f(yu.w);
    float4 r;
    r.x = fmaxf(y0, 0.f) + y0 * sc + sh + xv.x;
    r.y = fmaxf(y1, 0.f) + y1 * sc + sh + xv.y;
    r.z = fmaxf(y2, 0.f) + y2 * sc + sh + xv.z;
    r.w = fmaxf(y3, 0.f) + y3 * sc + sh + xv.w;
    ((float4*)out)[i] = r;
  }
}

// ---------------------------------------------------------------------------
extern "C" void kernel_launch(void* const* d_in, const int* in_sizes, int n_in,
                              void* d_out, int out_size, void* d_ws, size_t ws_size,
                              hipStream_t stream) {
  const float* x     = (const float*)d_in[0];
  const float* A     = (const float*)d_in[1];
  const float* w1    = (const float*)d_in[2];
  const float* b1    = (const float*)d_in[3];
  const float* w2    = (const float*)d_in[4];
  const float* b2    = (const float*)d_in[5];
  const float* w3    = (const float*)d_in[6];
  const float* b3    = (const float*)d_in[7];
  const float* w4    = (const float*)d_in[8];
  const float* b4    = (const float*)d_in[9];
  const float* alpha = (const float*)d_in[10];
  const float* gamma = (const float*)d_in[11];
  const float* beta  = (const float*)d_in[12];
  float* ws = (float*)d_ws;
  short8* w3f = (short8*)((char*)d_ws + W3F_BYTE_OFF);
  uint* attf_w = (uint*)((char*)d_ws + ATTF_BYTE_OFF);
  const ushort* attf_r = (const ushort*)((char*)d_ws + ATTF_BYTE_OFF);
  ushort* yg = (ushort*)((char*)d_ws + Y_BYTE_OFF);
  float* out = (float*)d_out;

  k_xm<<<2048, 256, 0, stream>>>(x, ws);
  k_att<<<768, 256, 0, stream>>>(ws, A, w1, b1, w2, b2, w4, b4, alpha, attf_w);
  k_wpack<<<3, 512, 0, stream>>>(w3, w3f);
  k_fused<<<2048, 512, 0, stream>>>(x, w3f, b3, attf_r, ws + SSUM_OFF, ws + SSQ_OFF, yg);
  k_stats<<<1, 64, 0, stream>>>(ws + SSUM_OFF, ws + SSQ_OFF, gamma, beta,
                                ws + SCL_OFF, ws + SHF_OFF);
  k_final<<<2048, 256, 0, stream>>>(x, yg, ws + SCL_OFF, ws + SHF_OFF, out);
}